// Round 3
// baseline (406.709 us; speedup 1.0000x reference)
//
#include <hip/hip_runtime.h>
#include <cstdint>

// DisjointSet densify + gather, fused.
// father[i] <= i (forest, parents have smaller index). Root r: father[r]==r.
// Harness passes integer inputs as int32 -> father is const int* (64 MB),
// fully resident in the 256 MB Infinity Cache.
// Per-thread chase: avg depth ~0.72 (E[d] = e^{i/N} - 1).

typedef float f32x4 __attribute__((ext_vector_type(4)));

__global__ __launch_bounds__(256) void ds_densify_gather(
    const int* __restrict__ father,
    const float* __restrict__ values,
    float* __restrict__ out_root,   // d_out[0 .. n)
    float* __restrict__ out_val,    // d_out[n .. 2n)
    int n)
{
    int idx = (blockIdx.x * blockDim.x + threadIdx.x) * 4;
    if (idx >= n) return;

    // Coalesced 16B load of four int32 parents.
    int4 f4 = *reinterpret_cast<const int4*>(father + idx);
    int p[4] = { f4.x, f4.y, f4.z, f4.w };

    // Chase each chain to its root. First probe of a root hits the
    // just-loaded cacheline (L1). Deeper probes are random but L3-resident.
    #pragma unroll
    for (int j = 0; j < 4; ++j) {
        int pj = p[j];
        int g = father[pj];
        while (g != pj) { pj = g; g = father[pj]; }
        p[j] = pj;
    }

    // Gather values at roots.
    f32x4 v = { values[p[0]], values[p[1]], values[p[2]], values[p[3]] };
    f32x4 r = { (float)p[0], (float)p[1], (float)p[2], (float)p[3] };

    // Streamed outputs: nontemporal so 128MB of writes don't evict the
    // father/values tables from L2/L3.
    __builtin_nontemporal_store(r, reinterpret_cast<f32x4*>(out_root + idx));
    __builtin_nontemporal_store(v, reinterpret_cast<f32x4*>(out_val + idx));
}

extern "C" void kernel_launch(void* const* d_in, const int* in_sizes, int n_in,
                              void* d_out, int out_size, void* d_ws, size_t ws_size,
                              hipStream_t stream) {
    const int*   father = (const int*)d_in[0];
    const float* values = (const float*)d_in[1];
    int n = in_sizes[0];                 // 16,777,216
    float* out_root = (float*)d_out;     // f_conv as float32 (exact: ids < 2^24)
    float* out_val  = (float*)d_out + n; // gathered values

    int threads = 256;
    int elems_per_block = threads * 4;
    int blocks = (n + elems_per_block - 1) / elems_per_block;
    ds_densify_gather<<<blocks, threads, 0, stream>>>(
        father, values, out_root, out_val, n);
}